// Round 14
// baseline (387.689 us; speedup 1.0000x reference)
//
#include <hip/hip_runtime.h>

typedef unsigned short u16;
typedef __attribute__((ext_vector_type(8))) short s16x8;
typedef __attribute__((ext_vector_type(4))) short s16x4;
typedef __attribute__((ext_vector_type(4))) float f32x4;

typedef const __attribute__((address_space(1))) void gas_void;
typedef __attribute__((address_space(3))) void las_void;

__device__ inline u16 f2bf(float f){
  union { float f; unsigned u; } c; c.f = f;
  unsigned r = c.u + 0x7fffu + ((c.u >> 16) & 1u);
  return (u16)(r >> 16);
}
__device__ inline float bf2f(u16 b){
  union { unsigned u; float f; } c; c.u = ((unsigned)b) << 16;
  return c.f;
}

// ---------------- fp32 -> bf16 convert (vectorized, grid-stride) ----------------
extern "C" __global__ __launch_bounds__(256) void cvt_f32_bf16(
    const float* __restrict__ src, u16* __restrict__ dst, int n4){
  int stride = gridDim.x * blockDim.x;
  for (int i = blockIdx.x * blockDim.x + threadIdx.x; i < n4; i += stride){
    float4 f = reinterpret_cast<const float4*>(src)[i];
    s16x4 o;
    o[0] = (short)f2bf(f.x); o[1] = (short)f2bf(f.y);
    o[2] = (short)f2bf(f.z); o[3] = (short)f2bf(f.w);
    reinterpret_cast<s16x4*>(dst)[i] = o;
  }
}

// ------- fused convert of the 3 weight matrices into one stacked 3072x1024 ------
extern "C" __global__ __launch_bounds__(256) void cvt_w3(
    const float* __restrict__ w0, const float* __restrict__ w1,
    const float* __restrict__ w2, u16* __restrict__ dst, int n4each){
  int stride = gridDim.x * blockDim.x;
  int total = 3 * n4each;
  for (int i = blockIdx.x * blockDim.x + threadIdx.x; i < total; i += stride){
    int w = i / n4each, off = i - w * n4each;
    const float* src = w == 0 ? w0 : w == 1 ? w1 : w2;
    float4 f = reinterpret_cast<const float4*>(src)[off];
    s16x4 o;
    o[0] = (short)f2bf(f.x); o[1] = (short)f2bf(f.y);
    o[2] = (short)f2bf(f.z); o[3] = (short)f2bf(f.w);
    reinterpret_cast<s16x4*>(dst)[i] = o;
  }
}

// ------ 8-way bf16 partial reduction: out = sum_z p[z] (f32 accumulate) ---------
extern "C" __global__ __launch_bounds__(256) void reduce8bf(
    const u16* __restrict__ p, float* __restrict__ out, int n8, long stride8){
  int gs = gridDim.x * blockDim.x;
  for (int i = blockIdx.x * blockDim.x + threadIdx.x; i < n8; i += gs){
    float a[8] = {0.f,0.f,0.f,0.f,0.f,0.f,0.f,0.f};
    #pragma unroll
    for (int z = 0; z < 8; ++z){
      s16x8 b = reinterpret_cast<const s16x8*>(p)[i + z * stride8];
      #pragma unroll
      for (int j = 0; j < 8; ++j) a[j] += bf2f((u16)b[j]);
    }
    float4 o0 = {a[0], a[1], a[2], a[3]};
    float4 o1 = {a[4], a[5], a[6], a[7]};
    reinterpret_cast<float4*>(out)[2 * i]     = o0;
    reinterpret_cast<float4*>(out)[2 * i + 1] = o1;
  }
}

// ------------- 128x128 bf16 GEMM, BK=64, 2 blocks/CU, 1-barrier/K-tile ----------
// Same verified components as the 334us round-13 kernel, tile shrunk 256->128:
// LDS 2dbuf x (A 16KB + B 16KB) = 64 KB -> 2 blocks/CU co-resident; an
// independent block fills the barrier/vmcnt/LDS-latency stalls (the measured
// ~4000 cy/tile residue at occupancy 1). 256 thr = 4 waves (2M x 2N), per-wave
// 64x64 output (acc[4][4] f32x4). Tile body: mid-tile staging (r12 lesson:
// stage-at-tile-start regresses), vmcnt(0) + one barrier per tile.
// T2 swizzle (verified conflict-free for 128B rows, unchanged by tile size):
// chunk ^= (row & 7), linear LDS dest + inverse-swizzled global src (involution).
// LESSON (r6, r11): do NOT fuse the projections (L2 thrash).
// LESSON (r10): chunk^=(row&7) is only verified for 128B rows (BK=64).
#define BM 128
#define BN 128
#define BK 64

__device__ inline void stage128(const u16* __restrict__ g, int ld, int row0, int k0,
                                u16* lds, int tid){
  const int wave = tid >> 6;
  #pragma unroll
  for (int j = 0; j < 4; ++j){
    int c = j * 256 + tid;          // dest 16B-chunk index (128 rows x 8 chunks)
    int row = c >> 3, sch = c & 7;
    int ch = sch ^ (row & 7);       // inverse-swizzled source chunk
    const u16* src = g + (long)(row0 + row) * ld + k0 + ch * 8;
    u16* dst = lds + (size_t)(j * 256 + wave * 64) * 8;  // wave-uniform base
    __builtin_amdgcn_global_load_lds((gas_void*)src, (las_void*)dst, 16, 0, 0);
  }
}

#define BARRIER() do { asm volatile("" ::: "memory"); \
                       __builtin_amdgcn_s_barrier();  \
                       asm volatile("" ::: "memory"); } while (0)

// EPI: 0 = bf16 out (+bias, scale); 1 = bf16 transposed "Vt" out [b][e][t] (+bias);
//      2 = bf16 out, z-indexed via sCz (PV partials; no bias)
template<int EPI>
__global__ __launch_bounds__(256, 2) void gemm128(
    const u16* __restrict__ A, const u16* __restrict__ B, void* __restrict__ C,
    const float* __restrict__ bias, float scale, int K,
    int lda, int ldb, int ldc, long sAz, long sBz, long sCz)
{
  __shared__ u16 As[2][BM * BK];
  __shared__ u16 Bs[2][BN * BK];
  const int tid = threadIdx.x;
  const int lane = tid & 63, wave = tid >> 6;
  const int wm = (wave >> 1) * 64, wn = (wave & 1) * 64;

  // T1: bijective XCD chunking (nwg % 8 == 0 in all launches) + paired-row order
  const int gx = gridDim.x;
  const int nwg = gx * gridDim.y;
  const int hw = blockIdx.y * gx + blockIdx.x;
  const int lg = (hw & 7) * (nwg >> 3) + (hw >> 3);
  const int pr  = lg / (2 * gx);          // A row-pair index   (gy even always)
  const int rem = lg - pr * 2 * gx;       // 0 .. 2*gx-1
  const int bm = (pr * 2 + (rem & 1)) * BM;
  const int bn = (rem >> 1) * BN;
  const int z = blockIdx.z;
  A += (long)z * sAz; B += (long)z * sBz;

  f32x4 acc[4][4];
  #pragma unroll
  for (int i = 0; i < 4; ++i)
    #pragma unroll
    for (int j = 0; j < 4; ++j) acc[i][j] = (f32x4){0.f, 0.f, 0.f, 0.f};

  const int lrow = lane & 15, lkg = lane >> 4;
  const int nt = K >> 6;

  // fragment reads (swizzled chunk index); row stride = 128 B
  auto lda4 = [&](s16x8* d, const u16* base, int kk){
    #pragma unroll
    for (int i = 0; i < 4; ++i){
      int row = wm + i * 16 + lrow;
      int ch = (kk * 4 + lkg) ^ (row & 7);
      d[i] = *reinterpret_cast<const s16x8*>(
          reinterpret_cast<const char*>(base) + row * 128 + ch * 16);
    }
  };
  auto ldb4 = [&](s16x8* d, const u16* base, int kk){
    #pragma unroll
    for (int j = 0; j < 4; ++j){
      int row = wn + j * 16 + lrow;
      int ch = (kk * 4 + lkg) ^ (row & 7);
      d[j] = *reinterpret_cast<const s16x8*>(
          reinterpret_cast<const char*>(base) + row * 128 + ch * 16);
    }
  };

  #define MFMACL(AF, BF)                                                       \
    _Pragma("unroll")                                                          \
    for (int i_ = 0; i_ < 4; ++i_)                                             \
      _Pragma("unroll")                                                        \
      for (int j_ = 0; j_ < 4; ++j_)                                           \
        acc[i_][j_] = __builtin_amdgcn_mfma_f32_16x16x32_bf16(                 \
            AF[i_], BF[j_], acc[i_][j_], 0, 0, 0);

  // prologue: stage tile 0, gate it
  stage128(A, lda, bm, 0, As[0], tid);
  stage128(B, ldb, bn, 0, Bs[0], tid);
  asm volatile("s_waitcnt vmcnt(0)" ::: "memory");
  BARRIER();

  for (int t = 0; t < nt; ++t){
    const int cur = t & 1, nxt = cur ^ 1;
    const bool pf = (t + 1) < nt;
    const int k1 = (t + 1) << 6;
    const u16* as = As[cur];
    const u16* bs = Bs[cur];
    s16x8 af0[4], af1[4], bfr0[4], bfr1[4];

    // cluster 0 reads (kk0)
    ldb4(bfr0, bs, 0);
    lda4(af0, as, 0);
    // cluster-1 reads + A-stage issued before cluster-0 MFMA retires (mid-tile)
    ldb4(bfr1, bs, 1);
    if (pf) stage128(A, lda, bm, k1, As[nxt], tid);
    __builtin_amdgcn_s_setprio(1);
    MFMACL(af0, bfr0);                               // kk0
    __builtin_amdgcn_s_setprio(0);
    lda4(af1, as, 1);
    if (pf) stage128(B, ldb, bn, k1, Bs[nxt], tid);
    __builtin_amdgcn_s_setprio(1);
    MFMACL(af1, bfr1);                               // kk1
    __builtin_amdgcn_s_setprio(0);

    asm volatile("s_waitcnt vmcnt(0)" ::: "memory"); // own stages landed
    BARRIER();                                       // publish t+1; protect buf reuse
  }

  // C/D layout (verified m89/m91): row = (lane>>4)*4 + r, col = lane&15
  #pragma unroll
  for (int i = 0; i < 4; ++i){
    #pragma unroll
    for (int j = 0; j < 4; ++j){
      #pragma unroll
      for (int r = 0; r < 4; ++r){
        int row = bm + wm + i * 16 + lkg * 4 + r;
        int col = bn + wn + j * 16 + lrow;
        float v = acc[i][j][r] * scale;
        if (EPI == 0){
          if (bias) v += bias[col];
          reinterpret_cast<u16*>(C)[(long)z * sCz + (long)row * ldc + col] = f2bf(v);
        } else if (EPI == 1){
          if (bias) v += bias[col];
          int b = row >> 11, tt = row & 2047;          // row = b*2048 + t
          reinterpret_cast<u16*>(C)[((long)b << 21) + ((long)col << 11) + tt] = f2bf(v);
        } else {
          // bf16 PV partial (error budget: ~2.4e-5/partial, x sqrt(8) ~ 7e-5)
          reinterpret_cast<u16*>(C)[(long)z * sCz + (long)row * ldc + col] = f2bf(v);
        }
      }
    }
  }
  #undef MFMACL
}

// -------- wave-per-row softmax over 2048-wide bf16 rows (no LDS, shfl only) -----
extern "C" __global__ __launch_bounds__(512) void softmax_rows_w(
    u16* __restrict__ S, int rows){
  const int lane = threadIdx.x & 63;
  const int gw = blockIdx.x * (blockDim.x >> 6) + (threadIdx.x >> 6);
  const int nw = gridDim.x * (blockDim.x >> 6);
  for (int row = gw; row < rows; row += nw){
    u16* p = S + (long)row * 2048;
    float v[32];
    float m = -3.4e38f;
    #pragma unroll
    for (int c = 0; c < 4; ++c){
      s16x8 vv = reinterpret_cast<const s16x8*>(p)[c * 64 + lane];
      #pragma unroll
      for (int j = 0; j < 8; ++j){
        float f = bf2f((u16)vv[j]);
        v[c * 8 + j] = f; m = fmaxf(m, f);
      }
    }
    #pragma unroll
    for (int o = 32; o; o >>= 1) m = fmaxf(m, __shfl_xor(m, o));
    float s = 0.f;
    #pragma unroll
    for (int j = 0; j < 32; ++j){ v[j] = __expf(v[j] - m); s += v[j]; }
    #pragma unroll
    for (int o = 32; o; o >>= 1) s += __shfl_xor(s, o);
    float inv = 1.0f / s;
    #pragma unroll
    for (int c = 0; c < 4; ++c){
      s16x8 ov;
      #pragma unroll
      for (int j = 0; j < 8; ++j) ov[j] = (short)f2bf(v[c * 8 + j] * inv);
      reinterpret_cast<s16x8*>(p)[c * 64 + lane] = ov;
    }
  }
}

extern "C" void kernel_launch(void* const* d_in, const int* in_sizes, int n_in,
                              void* d_out, int out_size, void* d_ws, size_t ws_size,
                              hipStream_t stream){
  const float* x  = (const float*)d_in[0];
  const float* Wq = (const float*)d_in[1];
  const float* bq = (const float*)d_in[2];
  const float* Wk = (const float*)d_in[3];
  const float* bk = (const float*)d_in[4];
  const float* Wv = (const float*)d_in[5];
  const float* bv = (const float*)d_in[6];

  const long NX = 16384L * 1024;   // x / Q / K / V element count
  const long NW = 1024L * 1024;    // one weight matrix
  const long NS = 8L * 2048 * 2048;

  u16* xbf = (u16*)d_ws;
  u16* Wb  = xbf + NX;             // stacked [Wq;Wk;Wv] = 3072 x 1024
  u16* Qb  = Wb + 3 * NW;
  u16* Kb  = Qb + NX;
  u16* Vtb = Kb + NX;              // [b][e][t]  (transposed V)
  u16* S   = Vtb + NX;             // scores, then softmax weights in place

  // After the scores GEMM, Qb+Kb are dead; reuse as the bf16 PV partial buffer
  // partial[z][row][col] (8 * 2048 * 1024 * 2 = 33.5 MB).
  u16* partial = Qb;

  size_t need = (size_t)(NX + 3 * NW + 3 * NX + NS) * 2;
  if (ws_size < need) return;      // leaves zeros -> distinguishable failure mode

  // 1) convert inputs to bf16 (x; 3 weights fused)
  cvt_f32_bf16<<<2048, 256, 0, stream>>>(x, xbf, (int)(NX / 4));
  cvt_w3<<<768, 256, 0, stream>>>(Wq, Wk, Wv, Wb, (int)(NW / 4));

  // 2) projections: three SEPARATE dispatches (each B-panel 2MB, L2-resident)
  gemm128<0><<<dim3(8, 128, 1), 256, 0, stream>>>(
      xbf, Wb,          Qb,  bq, 1.f, 1024, 1024, 1024, 1024, 0, 0, 0);
  gemm128<0><<<dim3(8, 128, 1), 256, 0, stream>>>(
      xbf, Wb + NW,     Kb,  bk, 1.f, 1024, 1024, 1024, 1024, 0, 0, 0);
  gemm128<1><<<dim3(8, 128, 1), 256, 0, stream>>>(
      xbf, Wb + 2 * NW, Vtb, bv, 1.f, 1024, 1024, 1024, 0,    0, 0, 0);

  // 3) scores: S[b] = (Q[b] · K[b]^T) / 32, all batches via grid.z
  gemm128<0><<<dim3(16, 16, 8), 256, 0, stream>>>(
      Qb, Kb, S, nullptr, 0.03125f, 1024, 1024, 1024, 2048,
      2048L * 1024, 2048L * 1024, 2048L * 2048);

  // 4) softmax in place (wave per row, register-resident)
  softmax_rows_w<<<256, 512, 0, stream>>>(S, 8 * 2048);

  // 5) partial[z] = (1/8) * P[z] · V[z]   (split-K over batch, bf16 partials)
  gemm128<2><<<dim3(8, 16, 8), 256, 0, stream>>>(
      S, Vtb, partial, nullptr, 0.125f, 2048, 2048, 2048, 1024,
      2048L * 2048, 1024L * 2048, 2048L * 1024);

  // 6) out = sum_z partial[z]  (bf16 -> f32)
  reduce8bf<<<1024, 256, 0, stream>>>(
      partial, (float*)d_out, (int)(2048L * 1024 / 8), 2048L * 1024 / 8);
}

// Round 15
// 332.625 us; speedup vs baseline: 1.1655x; 1.1655x over previous
//
#include <hip/hip_runtime.h>

typedef unsigned short u16;
typedef __attribute__((ext_vector_type(8))) short s16x8;
typedef __attribute__((ext_vector_type(4))) short s16x4;
typedef __attribute__((ext_vector_type(4))) float f32x4;

typedef const __attribute__((address_space(1))) void gas_void;
typedef __attribute__((address_space(3))) void las_void;

__device__ inline u16 f2bf(float f){
  union { float f; unsigned u; } c; c.f = f;
  unsigned r = c.u + 0x7fffu + ((c.u >> 16) & 1u);
  return (u16)(r >> 16);
}
__device__ inline float bf2f(u16 b){
  union { unsigned u; float f; } c; c.u = ((unsigned)b) << 16;
  return c.f;
}

// ---------------- fp32 -> bf16 convert (vectorized, grid-stride) ----------------
extern "C" __global__ __launch_bounds__(256) void cvt_f32_bf16(
    const float* __restrict__ src, u16* __restrict__ dst, int n4){
  int stride = gridDim.x * blockDim.x;
  for (int i = blockIdx.x * blockDim.x + threadIdx.x; i < n4; i += stride){
    float4 f = reinterpret_cast<const float4*>(src)[i];
    s16x4 o;
    o[0] = (short)f2bf(f.x); o[1] = (short)f2bf(f.y);
    o[2] = (short)f2bf(f.z); o[3] = (short)f2bf(f.w);
    reinterpret_cast<s16x4*>(dst)[i] = o;
  }
}

// ------- fused convert of the 3 weight matrices into one stacked 3072x1024 ------
extern "C" __global__ __launch_bounds__(256) void cvt_w3(
    const float* __restrict__ w0, const float* __restrict__ w1,
    const float* __restrict__ w2, u16* __restrict__ dst, int n4each){
  int stride = gridDim.x * blockDim.x;
  int total = 3 * n4each;
  for (int i = blockIdx.x * blockDim.x + threadIdx.x; i < total; i += stride){
    int w = i / n4each, off = i - w * n4each;
    const float* src = w == 0 ? w0 : w == 1 ? w1 : w2;
    float4 f = reinterpret_cast<const float4*>(src)[off];
    s16x4 o;
    o[0] = (short)f2bf(f.x); o[1] = (short)f2bf(f.y);
    o[2] = (short)f2bf(f.z); o[3] = (short)f2bf(f.w);
    reinterpret_cast<s16x4*>(dst)[i] = o;
  }
}

// ------ 8-way bf16 partial reduction: out = sum_z p[z] (f32 accumulate) ---------
extern "C" __global__ __launch_bounds__(256) void reduce8bf(
    const u16* __restrict__ p, float* __restrict__ out, int n8, long stride8){
  int gs = gridDim.x * blockDim.x;
  for (int i = blockIdx.x * blockDim.x + threadIdx.x; i < n8; i += gs){
    float a[8] = {0.f,0.f,0.f,0.f,0.f,0.f,0.f,0.f};
    #pragma unroll
    for (int z = 0; z < 8; ++z){
      s16x8 b = reinterpret_cast<const s16x8*>(p)[i + z * stride8];
      #pragma unroll
      for (int j = 0; j < 8; ++j) a[j] += bf2f((u16)b[j]);
    }
    float4 o0 = {a[0], a[1], a[2], a[3]};
    float4 o1 = {a[4], a[5], a[6], a[7]};
    reinterpret_cast<float4*>(out)[2 * i]     = o0;
    reinterpret_cast<float4*>(out)[2 * i + 1] = o1;
  }
}

// ------------- 256x256 bf16 GEMM, BK=64, 1-barrier/K-tile pipeline --------------
// (measured-best structure: 333.8 us total, round 13)
// A: M x K row-major, B: N x K row-major. 512 thr = 8 waves (2M x 4N), per-wave
// 128x64 (acc[8][4] f32x4). LDS 2dbuf x 32KB x {A,B} = 128 KiB.
// Tile body: ds_reads + MFMA clusters interleaved; stage(t+1) issued MID-TILE
// (inside MFMA windows). vmcnt(0) + one barrier at tile end.
// T2 swizzle (verified conflict-free for 128B rows): chunk ^= (row & 7),
// applied as linear LDS dest + inverse-swizzled global source (involution).
// MEASURED LESSONS THIS SESSION:
//  r5:  8-phase lockstep (barrier per sub-phase) regresses (-4%)
//  r6/r11: fusing projections (columns or grid.z) thrashes 4MB/XCD L2 (-10/-25%)
//  r10: chunk^=(row&7) is only conflict-free for 128B rows (BK=64)
//  r12: stage-at-tile-start exposes staging issue cost (-18% on scores/PV)
//  r14: 128^2 tile halves arithmetic intensity, same waves/CU (-16%)
#define BM 256
#define BN 256
#define BK 64

__device__ inline void stage256(const u16* __restrict__ g, int ld, int row0, int k0,
                                u16* lds, int tid){
  const int wave = tid >> 6;
  #pragma unroll
  for (int j = 0; j < 4; ++j){
    int c = j * 512 + tid;          // dest 16B-chunk index (256 rows x 8 chunks)
    int row = c >> 3, sch = c & 7;
    int ch = sch ^ (row & 7);       // inverse-swizzled source chunk
    const u16* src = g + (long)(row0 + row) * ld + k0 + ch * 8;
    u16* dst = lds + (size_t)(j * 512 + wave * 64) * 8;  // wave-uniform base
    __builtin_amdgcn_global_load_lds((gas_void*)src, (las_void*)dst, 16, 0, 0);
  }
}

#define BARRIER() do { asm volatile("" ::: "memory"); \
                       __builtin_amdgcn_s_barrier();  \
                       asm volatile("" ::: "memory"); } while (0)

// EPI: 0 = bf16 out (+bias, scale); 1 = bf16 transposed "Vt" out [b][e][t] (+bias);
//      2 = bf16 out, z-indexed via sCz (PV partials; no bias)
template<int EPI>
__global__ __launch_bounds__(512, 2) void gemm256(
    const u16* __restrict__ A, const u16* __restrict__ B, void* __restrict__ C,
    const float* __restrict__ bias, float scale, int K,
    int lda, int ldb, int ldc, long sAz, long sBz, long sCz)
{
  __shared__ u16 As[2][BM * BK];
  __shared__ u16 Bs[2][BN * BK];
  const int tid = threadIdx.x;
  const int lane = tid & 63, wave = tid >> 6;
  const int wm = (wave >> 2) * 128, wn = (wave & 3) * 64;

  // T1: bijective XCD chunking (nwg % 8 == 0 in all launches) + paired-row order
  const int gx = gridDim.x;
  const int nwg = gx * gridDim.y;
  const int hw = blockIdx.y * gx + blockIdx.x;
  const int lg = (hw & 7) * (nwg >> 3) + (hw >> 3);
  const int pr  = lg / (2 * gx);          // A row-pair index   (gy even always)
  const int rem = lg - pr * 2 * gx;       // 0 .. 2*gx-1
  const int bm = (pr * 2 + (rem & 1)) * BM;
  const int bn = (rem >> 1) * BN;
  const int z = blockIdx.z;
  A += (long)z * sAz; B += (long)z * sBz;

  f32x4 acc[8][4];
  #pragma unroll
  for (int i = 0; i < 8; ++i)
    #pragma unroll
    for (int j = 0; j < 4; ++j) acc[i][j] = (f32x4){0.f, 0.f, 0.f, 0.f};

  const int lrow = lane & 15, lkg = lane >> 4;
  const int nt = K >> 6;

  // fragment reads (swizzled chunk index); row stride = 128 B
  auto lda4 = [&](s16x8* d, const u16* base, int ih, int kk){
    #pragma unroll
    for (int i = 0; i < 4; ++i){
      int row = wm + (ih * 4 + i) * 16 + lrow;
      int ch = (kk * 4 + lkg) ^ (row & 7);
      d[i] = *reinterpret_cast<const s16x8*>(
          reinterpret_cast<const char*>(base) + row * 128 + ch * 16);
    }
  };
  auto ldb4 = [&](s16x8* d, const u16* base, int kk){
    #pragma unroll
    for (int j = 0; j < 4; ++j){
      int row = wn + j * 16 + lrow;
      int ch = (kk * 4 + lkg) ^ (row & 7);
      d[j] = *reinterpret_cast<const s16x8*>(
          reinterpret_cast<const char*>(base) + row * 128 + ch * 16);
    }
  };

  #define MFMACL(AF, BF, RO)                                                   \
    _Pragma("unroll")                                                          \
    for (int i_ = 0; i_ < 4; ++i_)                                             \
      _Pragma("unroll")                                                        \
      for (int j_ = 0; j_ < 4; ++j_)                                           \
        acc[(RO) + i_][j_] = __builtin_amdgcn_mfma_f32_16x16x32_bf16(          \
            AF[i_], BF[j_], acc[(RO) + i_][j_], 0, 0, 0);

  // prologue: stage tile 0, gate it
  stage256(A, lda, bm, 0, As[0], tid);
  stage256(B, ldb, bn, 0, Bs[0], tid);
  asm volatile("s_waitcnt vmcnt(0)" ::: "memory");
  BARRIER();

  for (int t = 0; t < nt; ++t){
    const int cur = t & 1, nxt = cur ^ 1;
    const bool pf = (t + 1) < nt;
    const int k1 = (t + 1) << 6;
    const u16* as = As[cur];
    const u16* bs = Bs[cur];
    s16x8 af0[4], af1[4], bfr0[4], bfr1[4];

    // lookahead: p0 + p1 fragments
    ldb4(bfr0, bs, 0);
    lda4(af0, as, 0, 0);
    lda4(af1, as, 1, 0);
    __builtin_amdgcn_s_setprio(1);
    MFMACL(af0, bfr0, 0);                           // p0: kk0, rows 0-63
    __builtin_amdgcn_s_setprio(0);
    ldb4(bfr1, bs, 1);
    lda4(af0, as, 0, 1);                            // p2 frags (reuse af0)
    if (pf) stage256(A, lda, bm, k1, As[nxt], tid); // stage mid-tile (r9 order)
    __builtin_amdgcn_s_setprio(1);
    MFMACL(af1, bfr0, 4);                           // p1: kk0, rows 64-127
    __builtin_amdgcn_s_setprio(0);
    lda4(af1, as, 1, 1);                            // p3 frags (reuse af1)
    if (pf) stage256(B, ldb, bn, k1, Bs[nxt], tid);
    __builtin_amdgcn_s_setprio(1);
    MFMACL(af0, bfr1, 0);                           // p2: kk1, rows 0-63
    MFMACL(af1, bfr1, 4);                           // p3: kk1, rows 64-127
    __builtin_amdgcn_s_setprio(0);

    asm volatile("s_waitcnt vmcnt(0)" ::: "memory"); // own stages landed
    BARRIER();                                       // publish t+1; protect buf reuse
  }

  // C/D layout (verified m89/m91): row = (lane>>4)*4 + r, col = lane&15
  #pragma unroll
  for (int i = 0; i < 8; ++i){
    #pragma unroll
    for (int j = 0; j < 4; ++j){
      #pragma unroll
      for (int r = 0; r < 4; ++r){
        int row = bm + wm + i * 16 + lkg * 4 + r;
        int col = bn + wn + j * 16 + lrow;
        float v = acc[i][j][r] * scale;
        if (EPI == 0){
          if (bias) v += bias[col];
          reinterpret_cast<u16*>(C)[(long)z * sCz + (long)row * ldc + col] = f2bf(v);
        } else if (EPI == 1){
          if (bias) v += bias[col];
          int b = row >> 11, tt = row & 2047;          // row = b*2048 + t
          reinterpret_cast<u16*>(C)[((long)b << 21) + ((long)col << 11) + tt] = f2bf(v);
        } else {
          // bf16 PV partial (error budget: ~2.4e-5/partial, x sqrt(8) ~ 7e-5)
          reinterpret_cast<u16*>(C)[(long)z * sCz + (long)row * ldc + col] = f2bf(v);
        }
      }
    }
  }
  #undef MFMACL
}

// -------- wave-per-row softmax over 2048-wide bf16 rows (no LDS, shfl only) -----
extern "C" __global__ __launch_bounds__(512) void softmax_rows_w(
    u16* __restrict__ S, int rows){
  const int lane = threadIdx.x & 63;
  const int gw = blockIdx.x * (blockDim.x >> 6) + (threadIdx.x >> 6);
  const int nw = gridDim.x * (blockDim.x >> 6);
  for (int row = gw; row < rows; row += nw){
    u16* p = S + (long)row * 2048;
    float v[32];
    float m = -3.4e38f;
    #pragma unroll
    for (int c = 0; c < 4; ++c){
      s16x8 vv = reinterpret_cast<const s16x8*>(p)[c * 64 + lane];
      #pragma unroll
      for (int j = 0; j < 8; ++j){
        float f = bf2f((u16)vv[j]);
        v[c * 8 + j] = f; m = fmaxf(m, f);
      }
    }
    #pragma unroll
    for (int o = 32; o; o >>= 1) m = fmaxf(m, __shfl_xor(m, o));
    float s = 0.f;
    #pragma unroll
    for (int j = 0; j < 32; ++j){ v[j] = __expf(v[j] - m); s += v[j]; }
    #pragma unroll
    for (int o = 32; o; o >>= 1) s += __shfl_xor(s, o);
    float inv = 1.0f / s;
    #pragma unroll
    for (int c = 0; c < 4; ++c){
      s16x8 ov;
      #pragma unroll
      for (int j = 0; j < 8; ++j) ov[j] = (short)f2bf(v[c * 8 + j] * inv);
      reinterpret_cast<s16x8*>(p)[c * 64 + lane] = ov;
    }
  }
}

extern "C" void kernel_launch(void* const* d_in, const int* in_sizes, int n_in,
                              void* d_out, int out_size, void* d_ws, size_t ws_size,
                              hipStream_t stream){
  const float* x  = (const float*)d_in[0];
  const float* Wq = (const float*)d_in[1];
  const float* bq = (const float*)d_in[2];
  const float* Wk = (const float*)d_in[3];
  const float* bk = (const float*)d_in[4];
  const float* Wv = (const float*)d_in[5];
  const float* bv = (const float*)d_in[6];

  const long NX = 16384L * 1024;   // x / Q / K / V element count
  const long NW = 1024L * 1024;    // one weight matrix
  const long NS = 8L * 2048 * 2048;

  u16* xbf = (u16*)d_ws;
  u16* Wb  = xbf + NX;             // stacked [Wq;Wk;Wv] = 3072 x 1024
  u16* Qb  = Wb + 3 * NW;
  u16* Kb  = Qb + NX;
  u16* Vtb = Kb + NX;              // [b][e][t]  (transposed V)
  u16* S   = Vtb + NX;             // scores, then softmax weights in place

  // After the scores GEMM, Qb+Kb are dead; reuse as the bf16 PV partial buffer
  // partial[z][row][col] (8 * 2048 * 1024 * 2 = 33.5 MB).
  u16* partial = Qb;

  size_t need = (size_t)(NX + 3 * NW + 3 * NX + NS) * 2;
  if (ws_size < need) return;      // leaves zeros -> distinguishable failure mode

  // 1) convert inputs to bf16 (x; 3 weights fused)
  cvt_f32_bf16<<<2048, 256, 0, stream>>>(x, xbf, (int)(NX / 4));
  cvt_w3<<<768, 256, 0, stream>>>(Wq, Wk, Wv, Wb, (int)(NW / 4));

  // 2) projections: three SEPARATE dispatches (each B-panel 2MB, L2-resident)
  gemm256<0><<<dim3(4, 64, 1), 512, 0, stream>>>(
      xbf, Wb,          Qb,  bq, 1.f, 1024, 1024, 1024, 1024, 0, 0, 0);
  gemm256<0><<<dim3(4, 64, 1), 512, 0, stream>>>(
      xbf, Wb + NW,     Kb,  bk, 1.f, 1024, 1024, 1024, 1024, 0, 0, 0);
  gemm256<1><<<dim3(4, 64, 1), 512, 0, stream>>>(
      xbf, Wb + 2 * NW, Vtb, bv, 1.f, 1024, 1024, 1024, 0,    0, 0, 0);

  // 3) scores: S[b] = (Q[b] · K[b]^T) / 32, all batches via grid.z
  gemm256<0><<<dim3(8, 8, 8), 512, 0, stream>>>(
      Qb, Kb, S, nullptr, 0.03125f, 1024, 1024, 1024, 2048,
      2048L * 1024, 2048L * 1024, 2048L * 2048);

  // 4) softmax in place (wave per row, register-resident)
  softmax_rows_w<<<256, 512, 0, stream>>>(S, 8 * 2048);

  // 5) partial[z] = (1/8) * P[z] · V[z]   (split-K over batch, bf16 partials)
  gemm256<2><<<dim3(4, 8, 8), 512, 0, stream>>>(
      S, Vtb, partial, nullptr, 0.125f, 2048, 2048, 2048, 1024,
      2048L * 2048, 1024L * 2048, 2048L * 1024);

  // 6) out = sum_z partial[z]  (bf16 -> f32)
  reduce8bf<<<1024, 256, 0, stream>>>(
      partial, (float*)d_out, (int)(2048L * 1024 / 8), 2048L * 1024 / 8);
}